// Round 11
// baseline (236.177 us; speedup 1.0000x reference)
//
#include <hip/hip_runtime.h>
#include <hip/hip_fp16.h>

#define NPTS 262144
#define EMB  256
#define NROWS 2048

typedef _Float16 half_t;
typedef __attribute__((ext_vector_type(8))) _Float16 half8;
typedef __attribute__((ext_vector_type(2))) _Float16 half2v;

// ---------------------------------------------------------------------------
// Kernel 1: T2[a,i,o] = (30/4)/(2pi) * sum_e tables[a,i,e] * W1[o,e], fp16.
// ---------------------------------------------------------------------------
__global__ __launch_bounds__(256) void t2_precompute_kernel(
    const float* __restrict__ tables,   // [4][512][256]
    const float* __restrict__ W1,       // [256][256]
    half_t* __restrict__ T2)            // [2048][256]
{
    __shared__ __align__(16) float arow[8][EMB];
    const int row0 = blockIdx.x * 8;
    const int o = threadIdx.x;

    #pragma unroll
    for (int r = 0; r < 8; ++r)
        arow[r][o] = tables[(row0 + r) * EMB + o];
    __syncthreads();

    float acc[8] = {0.f, 0.f, 0.f, 0.f, 0.f, 0.f, 0.f, 0.f};
    const float4* __restrict__ w1v = reinterpret_cast<const float4*>(W1 + o * EMB);
    for (int ec = 0; ec < EMB / 4; ++ec) {
        const float4 w4 = w1v[ec];
        #pragma unroll
        for (int r = 0; r < 8; ++r) {
            const float4 a4 = *reinterpret_cast<const float4*>(&arow[r][ec * 4]);
            acc[r] = fmaf(w4.x, a4.x, acc[r]);
            acc[r] = fmaf(w4.y, a4.y, acc[r]);
            acc[r] = fmaf(w4.z, a4.z, acc[r]);
            acc[r] = fmaf(w4.w, a4.w, acc[r]);
        }
    }
    const float s = 7.5f * 0.15915494309189535f;   // (30/4)/(2pi)
    #pragma unroll
    for (int r = 0; r < 8; ++r)
        T2[(row0 + r) * EMB + o] = (half_t)(s * acc[r]);
}

// ---------------------------------------------------------------------------
// DPP butterfly add over 16 lanes — VALU pipe.
// ---------------------------------------------------------------------------
template <int CTRL>
__device__ __forceinline__ float dpp_add(float v) {
    const int vi = __builtin_bit_cast(int, v);
    const int sh = __builtin_amdgcn_update_dpp(0, vi, CTRL, 0xF, 0xF, true);
    return v + __builtin_bit_cast(float, sh);
}
__device__ __forceinline__ float reduce16(float v) {
    v = dpp_add<0xB1>(v);    // quad_perm xor1
    v = dpp_add<0x4E>(v);    // quad_perm xor2
    v = dpp_add<0x141>(v);   // row_half_mirror
    v = dpp_add<0x140>(v);   // row_mirror
    return v;
}

// ---------------------------------------------------------------------------
// Kernel 2: 16 lanes/point, 4 points/wave, 16 iterations/wave (grid 1024,
// single resident batch). Half-phase software pipeline: while quad k's
// A-phase (lerp+sin+dot) executes, quad k+1's A-half loads are in flight,
// and likewise for B. sched_barrier(0) pins load-issue ahead of compute.
// ---------------------------------------------------------------------------
__global__ __launch_bounds__(256, 4) void eval_kernel(
    const float* __restrict__ coords,      // [N][2]
    const half_t* __restrict__ T2,         // [2048][256]
    const float* __restrict__ b1,
    const float* __restrict__ W2,
    const float* __restrict__ b2,
    float* __restrict__ out)
{
    const int lane = threadIdx.x & 63;
    const int g    = lane >> 4;            // point slot within wave
    const int l16  = lane & 15;
    const int dA   = l16 * 8;              // dims dA..dA+7   (row half A)
    const int dB   = 128 + l16 * 8;        // dims dB..dB+7   (row half B)

    const int wave = blockIdx.x * 4 + (threadIdx.x >> 6);   // 0..4095
    const int q0   = wave * 16;

    // ---- hoisted per-lane constants ----
    const float sb = 30.f * 0.15915494309189535f;
    half8 biasA, biasB;
    #pragma unroll
    for (int i = 0; i < 8; ++i) {
        biasA[i] = (half_t)(sb * b1[dA + i]);
        biasB[i] = (half_t)(sb * b1[dB + i]);
    }
    half2v w2A[3][4], w2B[3][4];
    #pragma unroll
    for (int j = 0; j < 3; ++j)
        #pragma unroll
        for (int k = 0; k < 4; ++k) {
            w2A[j][k][0] = (half_t)W2[j * EMB + dA + 2 * k];
            w2A[j][k][1] = (half_t)W2[j * EMB + dA + 2 * k + 1];
            w2B[j][k][0] = (half_t)W2[j * EMB + dB + 2 * k];
            w2B[j][k][1] = (half_t)W2[j * EMB + dB + 2 * k + 1];
        }
    const float ob0 = b2[0], ob1 = b2[1], ob2 = b2[2];

    int Ca[4];
    #pragma unroll
    for (int a = 0; a < 4; ++a) Ca[a] = (a << 18) + (l16 << 4);

    const char* __restrict__ T2b = reinterpret_cast<const char*>(T2);
    const float TMAX = 0.9995f * 511.0f;

    // ---- helpers ----
    auto calcq = [&](int q, int rb[4], half2v pw[4], int& pOut) {
        const int p = 4 * q + g;
        pOut = p;
        const float2 cf = *reinterpret_cast<const float2*>(coords + 2 * p);
        const float txr = __builtin_amdgcn_fmed3f(fmaf(cf.x, 255.5f, 255.5f), 0.f, 511.f);
        const float tyr = __builtin_amdgcn_fmed3f(fmaf(cf.y, 255.5f, 255.5f), 0.f, 511.f);
        float t[4];
        t[0] = fminf(txr, TMAX);
        t[1] = fminf(tyr, TMAX);
        t[2] = fminf((txr + tyr) * 0.5f, TMAX);
        t[3] = fminf(fmaf(txr - tyr, 0.5f, 255.5f), TMAX);
        #pragma unroll
        for (int a = 0; a < 4; ++a) {
            const int i0 = (int)t[a];
            const float w = t[a] - (float)i0;
            rb[a] = (i0 << 9) + Ca[a];
            pw[a] = __builtin_bit_cast(half2v,
                        __builtin_amdgcn_cvt_pkrtz(1.f - w, w));
        }
    };

    // staging buffers (single set, rotated by WAR renaming inside the loop)
    half8 A0[4], A1[4], B0[4], B1[4];

    auto loadA = [&](const int rb[4]) {
        #pragma unroll
        for (int a = 0; a < 4; ++a) {
            A0[a] = *reinterpret_cast<const half8*>(T2b + rb[a]);
            A1[a] = *reinterpret_cast<const half8*>(T2b + rb[a] + 512);
        }
    };
    auto loadB = [&](const int rb[4]) {
        #pragma unroll
        for (int a = 0; a < 4; ++a) {
            B0[a] = *reinterpret_cast<const half8*>(T2b + rb[a] + 256);
            B1[a] = *reinterpret_cast<const half8*>(T2b + rb[a] + 768);
        }
    };
    auto dots = [&](const half8& acc, const half2v (&w2)[3][4],
                    float& q0r, float& q1r, float& q2r) {
        #pragma unroll
        for (int k = 0; k < 4; ++k) {
            const float s0 = __builtin_amdgcn_sinf((float)acc[2 * k]);
            const float s1 = __builtin_amdgcn_sinf((float)acc[2 * k + 1]);
            const half2v hp = __builtin_bit_cast(half2v,
                                  __builtin_amdgcn_cvt_pkrtz(s0, s1));
            q0r = __builtin_amdgcn_fdot2(hp, w2[0][k], q0r, false);
            q1r = __builtin_amdgcn_fdot2(hp, w2[1][k], q1r, false);
            q2r = __builtin_amdgcn_fdot2(hp, w2[2][k], q2r, false);
        }
    };

    // ---- prologue: quad q0 data in flight, quad q0+1 meta ready ----
    int rbX[4]; half2v wX[4]; int pX;
    int rbY[4]; half2v wY[4]; int pY;

    calcq(q0, rbX, wX, pX);
    loadA(rbX);
    loadB(rbX);
    __builtin_amdgcn_sched_barrier(0);
    calcq(q0 + 1, rbY, wY, pY);

    #pragma unroll 2
    for (int k = 0; k < 16; ++k) {
        const bool more = (k < 15);

        // ---- A phase: consume A(X), issue A(Y) ----
        half8 accA = biasA;
        #pragma unroll
        for (int a = 0; a < 4; ++a) {
            accA = A0[a] * wX[a][0] + accA;
            accA = A1[a] * wX[a][1] + accA;
        }
        if (more) loadA(rbY);
        __builtin_amdgcn_sched_barrier(0);

        float q0r = 0.f, q1r = 0.f, q2r = 0.f;
        dots(accA, w2A, q0r, q1r, q2r);

        // ---- B phase: consume B(X), issue B(Y) ----
        half8 accB = biasB;
        #pragma unroll
        for (int a = 0; a < 4; ++a) {
            accB = B0[a] * wX[a][0] + accB;
            accB = B1[a] * wX[a][1] + accB;
        }
        if (more) loadB(rbY);
        __builtin_amdgcn_sched_barrier(0);

        dots(accB, w2B, q0r, q1r, q2r);

        q0r = reduce16(q0r);
        q1r = reduce16(q1r);
        q2r = reduce16(q2r);

        if (l16 == 0) {
            *reinterpret_cast<float3*>(out + 3 * pX) =
                make_float3(q0r + ob0, q1r + ob1, q2r + ob2);
        }

        // ---- rotate meta: X <- Y; compute meta for quad k+2 ----
        #pragma unroll
        for (int a = 0; a < 4; ++a) { rbX[a] = rbY[a]; wX[a] = wY[a]; }
        pX = pY;
        const int qn = q0 + ((k + 2 < 16) ? (k + 2) : 15);
        calcq(qn, rbY, wY, pY);
    }
}

extern "C" void kernel_launch(void* const* d_in, const int* in_sizes, int n_in,
                              void* d_out, int out_size, void* d_ws, size_t ws_size,
                              hipStream_t stream) {
    const float* coords = (const float*)d_in[0];
    const float* tables = (const float*)d_in[1];
    const float* W1     = (const float*)d_in[2];
    const float* b1     = (const float*)d_in[3];
    const float* W2     = (const float*)d_in[4];
    const float* b2     = (const float*)d_in[5];
    float* out = (float*)d_out;

    half_t* T2 = (half_t*)d_ws;   // 1 MiB scratch

    hipLaunchKernelGGL(t2_precompute_kernel, dim3(NROWS / 8), dim3(256), 0, stream,
                       tables, W1, T2);
    hipLaunchKernelGGL(eval_kernel, dim3(1024), dim3(256), 0, stream,
                       coords, T2, b1, W2, b2, out);
}

// Round 12
// 56.222 us; speedup vs baseline: 4.2008x; 4.2008x over previous
//
#include <hip/hip_runtime.h>
#include <hip/hip_fp16.h>

#define NPTS 262144
#define EMB  256
#define NROWS 2048

typedef _Float16 half_t;
typedef __attribute__((ext_vector_type(8))) _Float16 half8;
typedef __attribute__((ext_vector_type(2))) _Float16 half2v;

// ---------------------------------------------------------------------------
// Kernel 1: T2[a,i,o] = (30/4)/(2pi) * sum_e tables[a,i,e] * W1[o,e], fp16.
// ---------------------------------------------------------------------------
__global__ __launch_bounds__(256) void t2_precompute_kernel(
    const float* __restrict__ tables,   // [4][512][256]
    const float* __restrict__ W1,       // [256][256]
    half_t* __restrict__ T2)            // [2048][256]
{
    __shared__ __align__(16) float arow[8][EMB];
    const int row0 = blockIdx.x * 8;
    const int o = threadIdx.x;

    #pragma unroll
    for (int r = 0; r < 8; ++r)
        arow[r][o] = tables[(row0 + r) * EMB + o];
    __syncthreads();

    float acc[8] = {0.f, 0.f, 0.f, 0.f, 0.f, 0.f, 0.f, 0.f};
    const float4* __restrict__ w1v = reinterpret_cast<const float4*>(W1 + o * EMB);
    for (int ec = 0; ec < EMB / 4; ++ec) {
        const float4 w4 = w1v[ec];
        #pragma unroll
        for (int r = 0; r < 8; ++r) {
            const float4 a4 = *reinterpret_cast<const float4*>(&arow[r][ec * 4]);
            acc[r] = fmaf(w4.x, a4.x, acc[r]);
            acc[r] = fmaf(w4.y, a4.y, acc[r]);
            acc[r] = fmaf(w4.z, a4.z, acc[r]);
            acc[r] = fmaf(w4.w, a4.w, acc[r]);
        }
    }
    const float s = 7.5f * 0.15915494309189535f;   // (30/4)/(2pi)
    #pragma unroll
    for (int r = 0; r < 8; ++r)
        T2[(row0 + r) * EMB + o] = (half_t)(s * acc[r]);
}

// ---------------------------------------------------------------------------
// DPP butterfly add over 16 lanes — VALU pipe.
// ---------------------------------------------------------------------------
template <int CTRL>
__device__ __forceinline__ float dpp_add(float v) {
    const int vi = __builtin_bit_cast(int, v);
    const int sh = __builtin_amdgcn_update_dpp(0, vi, CTRL, 0xF, 0xF, true);
    return v + __builtin_bit_cast(float, sh);
}
__device__ __forceinline__ float reduce16(float v) {
    v = dpp_add<0xB1>(v);    // quad_perm xor1
    v = dpp_add<0x4E>(v);    // quad_perm xor2
    v = dpp_add<0x141>(v);   // row_half_mirror
    v = dpp_add<0x140>(v);   // row_mirror
    return v;
}

// ---------------------------------------------------------------------------
// Kernel 2: 16 lanes/point, 4 points/wave, 16 quads/wave (grid 1024).
// Explicit 2-deep pipeline with TWO NAMED buffer sets and an unconditional
// two-body loop: compute(quad k) from buf X, then reload buf X for quad k+2.
// No conditionals or dynamic indices touch the buffers (spill-safe).
// __launch_bounds__(256,2): 256-VGPR budget so both buffers stay in registers.
// ---------------------------------------------------------------------------
__global__ __launch_bounds__(256, 2) void eval_kernel(
    const float* __restrict__ coords,      // [N][2]
    const half_t* __restrict__ T2,         // [2048][256]
    const float* __restrict__ b1,
    const float* __restrict__ W2,
    const float* __restrict__ b2,
    float* __restrict__ out)
{
    const int lane = threadIdx.x & 63;
    const int g    = lane >> 4;            // point slot within wave
    const int l16  = lane & 15;
    const int dA   = l16 * 8;              // dims dA..dA+7   (row half A)
    const int dB   = 128 + l16 * 8;        // dims dB..dB+7   (row half B)

    const int wave  = blockIdx.x * 4 + (threadIdx.x >> 6);  // 0..4095
    const int qbase = wave * 16;

    // ---- hoisted per-lane constants ----
    const float sb = 30.f * 0.15915494309189535f;
    half8 biasA, biasB;
    #pragma unroll
    for (int i = 0; i < 8; ++i) {
        biasA[i] = (half_t)(sb * b1[dA + i]);
        biasB[i] = (half_t)(sb * b1[dB + i]);
    }
    half2v w2A[3][4], w2B[3][4];
    #pragma unroll
    for (int j = 0; j < 3; ++j)
        #pragma unroll
        for (int k = 0; k < 4; ++k) {
            w2A[j][k][0] = (half_t)W2[j * EMB + dA + 2 * k];
            w2A[j][k][1] = (half_t)W2[j * EMB + dA + 2 * k + 1];
            w2B[j][k][0] = (half_t)W2[j * EMB + dB + 2 * k];
            w2B[j][k][1] = (half_t)W2[j * EMB + dB + 2 * k + 1];
        }
    const float ob0 = b2[0], ob1 = b2[1], ob2 = b2[2];

    int Ca[4];
    #pragma unroll
    for (int a = 0; a < 4; ++a) Ca[a] = (a << 18) + (l16 << 4);

    const char* __restrict__ T2b = reinterpret_cast<const char*>(T2);
    const float TMAX = 0.9995f * 511.0f;

    // ---- helpers ----
    auto calcq = [&](int q, int rb[4], half2v pw[4], int& pOut) {
        const int p = 4 * q + g;
        pOut = p;
        const float2 cf = *reinterpret_cast<const float2*>(coords + 2 * p);
        const float txr = __builtin_amdgcn_fmed3f(fmaf(cf.x, 255.5f, 255.5f), 0.f, 511.f);
        const float tyr = __builtin_amdgcn_fmed3f(fmaf(cf.y, 255.5f, 255.5f), 0.f, 511.f);
        float t[4];
        t[0] = fminf(txr, TMAX);
        t[1] = fminf(tyr, TMAX);
        t[2] = fminf((txr + tyr) * 0.5f, TMAX);
        t[3] = fminf(fmaf(txr - tyr, 0.5f, 255.5f), TMAX);
        #pragma unroll
        for (int a = 0; a < 4; ++a) {
            const int i0 = (int)t[a];
            const float w = t[a] - (float)i0;
            rb[a] = (i0 << 9) + Ca[a];
            pw[a] = __builtin_bit_cast(half2v,
                        __builtin_amdgcn_cvt_pkrtz(1.f - w, w));
        }
    };
    auto loadset = [&](const int rb[4], half8 (&A0)[4], half8 (&A1)[4],
                       half8 (&B0)[4], half8 (&B1)[4]) {
        #pragma unroll
        for (int a = 0; a < 4; ++a) {
            A0[a] = *reinterpret_cast<const half8*>(T2b + rb[a]);
            A1[a] = *reinterpret_cast<const half8*>(T2b + rb[a] + 512);
            B0[a] = *reinterpret_cast<const half8*>(T2b + rb[a] + 256);
            B1[a] = *reinterpret_cast<const half8*>(T2b + rb[a] + 768);
        }
    };
    auto comp = [&](const half8 (&A0)[4], const half8 (&A1)[4],
                    const half8 (&B0)[4], const half8 (&B1)[4],
                    const half2v (&pw)[4], int p) {
        half8 accA = biasA;
        #pragma unroll
        for (int a = 0; a < 4; ++a) {
            accA = A0[a] * pw[a][0] + accA;
            accA = A1[a] * pw[a][1] + accA;
        }
        float q0r = 0.f, q1r = 0.f, q2r = 0.f;
        #pragma unroll
        for (int k = 0; k < 4; ++k) {
            const float s0 = __builtin_amdgcn_sinf((float)accA[2 * k]);
            const float s1 = __builtin_amdgcn_sinf((float)accA[2 * k + 1]);
            const half2v hp = __builtin_bit_cast(half2v,
                                  __builtin_amdgcn_cvt_pkrtz(s0, s1));
            q0r = __builtin_amdgcn_fdot2(hp, w2A[0][k], q0r, false);
            q1r = __builtin_amdgcn_fdot2(hp, w2A[1][k], q1r, false);
            q2r = __builtin_amdgcn_fdot2(hp, w2A[2][k], q2r, false);
        }
        half8 accB = biasB;
        #pragma unroll
        for (int a = 0; a < 4; ++a) {
            accB = B0[a] * pw[a][0] + accB;
            accB = B1[a] * pw[a][1] + accB;
        }
        #pragma unroll
        for (int k = 0; k < 4; ++k) {
            const float s0 = __builtin_amdgcn_sinf((float)accB[2 * k]);
            const float s1 = __builtin_amdgcn_sinf((float)accB[2 * k + 1]);
            const half2v hp = __builtin_bit_cast(half2v,
                                  __builtin_amdgcn_cvt_pkrtz(s0, s1));
            q0r = __builtin_amdgcn_fdot2(hp, w2B[0][k], q0r, false);
            q1r = __builtin_amdgcn_fdot2(hp, w2B[1][k], q1r, false);
            q2r = __builtin_amdgcn_fdot2(hp, w2B[2][k], q2r, false);
        }
        q0r = reduce16(q0r);
        q1r = reduce16(q1r);
        q2r = reduce16(q2r);
        if (l16 == 0) {
            *reinterpret_cast<float3*>(out + 3 * p) =
                make_float3(q0r + ob0, q1r + ob1, q2r + ob2);
        }
    };

    // ---- prologue: two quads in flight in two named buffer sets ----
    half8 A0a[4], A1a[4], B0a[4], B1a[4];   // buf a
    half8 A0b[4], A1b[4], B0b[4], B1b[4];   // buf b
    half2v wA[4], wB[4];
    int pA, pB;
    {
        int rb[4];
        calcq(qbase + 0, rb, wA, pA);
        loadset(rb, A0a, A1a, B0a, B1a);
    }
    {
        int rb[4];
        calcq(qbase + 1, rb, wB, pB);
        loadset(rb, A0b, A1b, B0b, B1b);
    }

    for (int k = 0; k < 16; k += 2) {
        // ---- body 0: compute quad k from buf a, reload buf a <- quad k+2 ----
        {
            int rbn[4]; half2v wn[4]; int pn;
            const int qn = qbase + ((k + 2 < 16) ? (k + 2) : 15);
            calcq(qn, rbn, wn, pn);
            comp(A0a, A1a, B0a, B1a, wA, pA);
            loadset(rbn, A0a, A1a, B0a, B1a);
            #pragma unroll
            for (int a = 0; a < 4; ++a) wA[a] = wn[a];
            pA = pn;
        }
        // ---- body 1: compute quad k+1 from buf b, reload buf b <- quad k+3 ----
        {
            int rbn[4]; half2v wn[4]; int pn;
            const int qn = qbase + ((k + 3 < 16) ? (k + 3) : 15);
            calcq(qn, rbn, wn, pn);
            comp(A0b, A1b, B0b, B1b, wB, pB);
            loadset(rbn, A0b, A1b, B0b, B1b);
            #pragma unroll
            for (int a = 0; a < 4; ++a) wB[a] = wn[a];
            pB = pn;
        }
    }
}

extern "C" void kernel_launch(void* const* d_in, const int* in_sizes, int n_in,
                              void* d_out, int out_size, void* d_ws, size_t ws_size,
                              hipStream_t stream) {
    const float* coords = (const float*)d_in[0];
    const float* tables = (const float*)d_in[1];
    const float* W1     = (const float*)d_in[2];
    const float* b1     = (const float*)d_in[3];
    const float* W2     = (const float*)d_in[4];
    const float* b2     = (const float*)d_in[5];
    float* out = (float*)d_out;

    half_t* T2 = (half_t*)d_ws;   // 1 MiB scratch

    hipLaunchKernelGGL(t2_precompute_kernel, dim3(NROWS / 8), dim3(256), 0, stream,
                       tables, W1, T2);
    hipLaunchKernelGGL(eval_kernel, dim3(1024), dim3(256), 0, stream,
                       coords, T2, b1, W2, b2, out);
}